// Round 10
// baseline (311.614 us; speedup 1.0000x reference)
//
#include <hip/hip_runtime.h>

typedef float v4f __attribute__((ext_vector_type(4)));

namespace {
constexpr int B_     = 8;
constexpr int NT_    = 256;
constexpr int NX_    = 256;
constexpr int NREC_  = 64;
constexpr int PIECES = 32;             // 256 blocks -> all 256 CUs
constexpr int IROWS  = 8;              // interior rows per strip
constexpr int G      = 16;             // steps per round
constexpr int ROUNDS = NT_ / G;        // 16 (15 exchanges)
constexpr int NB     = 10;             // 10 bands x 4 rows (R15 geometry)
constexpr int NTHR   = NB * 64;        // 640 threads
constexpr int NBLK   = B_ * PIECES;    // 256 blocks
constexpr float DT2  = 1e-6f;          // DT*DT
constexpr float KLAP = 1e-8f;          // DT*DT/(DH*DH)
constexpr size_t FLAGS_BYTES = 4096;
constexpr int RCAP = 6;
} // namespace

__device__ __forceinline__ float dpp_shr1(float v) {
    return __int_as_float(__builtin_amdgcn_update_dpp(
        0, __float_as_int(v), 0x138 /*WAVE_SHR1*/, 0xF, 0xF, true));
}
__device__ __forceinline__ float dpp_shl1(float v) {
    return __int_as_float(__builtin_amdgcn_update_dpp(
        0, __float_as_int(v), 0x130 /*WAVE_SHL1*/, 0xF, 0xF, true));
}

// R15 decomposition: wall = VALU(rows/CU) + residue, residue = per-step
// handoff chain (publish -> barrier -> halo read -> dependent VALU) x 256.
// R16 showed geometry can't shrink the chain. R17: 2-STEP FUSION -- 2-row
// halo, TWO time-steps per barrier -> 128 chains. Publish {A0,A1,B0} north +
// {A2,A3,B3} south; compute 6 temp rows (t+1, one into each neighbor) then 4
// final rows (t+2). +25% row-compute, DS 1.5x (neither binding). Trapezoid:
// compute cycle c iff 2c+1 <= cut, publish iff 2c-1 <= cut (frontier-checked:
// live (row,step) inputs identical to R15; garbage only in dead rows; ghosts
// fully refilled at exchange) -> bit-identical absmax.
__device__ __forceinline__ void store_v4_sys(float* p, v4f v) {
    asm volatile("global_store_dwordx4 %0, %1, off sc0 sc1"
                 :: "v"(p), "v"(v) : "memory");
}
__device__ __forceinline__ v4f load_v4_sys(const float* p) {
    v4f r;
    asm volatile("global_load_dwordx4 %0, %1, off sc0 sc1"
                 : "=v"(r) : "v"(p) : "memory");
    return r;
}

extern "C" __global__
__attribute__((amdgpu_flat_work_group_size(NTHR, NTHR), amdgpu_waves_per_eu(3, 4)))
void wave_reg_kernel(const float* __restrict__ x,
                     const float* __restrict__ vp,
                     const int* __restrict__ src_loc,
                     const int* __restrict__ rec_loc,
                     float* __restrict__ out,
                     int* __restrict__ flags,   // [256] monotone round counters
                     float* __restrict__ gbuf)  // [par2][256][lvl2][8][256]
{
    // pub slots per band: 0:A0 1:A1 2:B0 (north-facing) 3:A2 4:A3 5:B3 (south)
    __shared__ float pub[2][NB][6][256];      // 120 KB
    __shared__ float wav[NT_];                // 1 KB wavelet
    __shared__ float recbuf[G][NREC_];        // 4 KB receiver staging
    __shared__ unsigned char recown[NREC_];

    const int bid  = blockIdx.x;
    const int b    = bid & 7;
    const int p    = bid >> 3;             // 0..31
    const int blk  = b * PIECES + p;
    const int tid  = threadIdx.x;
    const int band = tid >> 6;             // wave id 0..9 -> 4 ext rows
    const int lane = tid & 63;
    const int c0   = lane << 2;            // first owned col (0..252)
    const int grt  = p * IROWS - G + (band << 2);  // global row of owned row 0

    // trapezoid cutoff (R13/R15 values): {3,7,11,15,16,16,15,11,7,3}
    const int cut = (band < 4) ? ((band << 2) + 3)
                  : ((band < 6) ? G : (39 - (band << 2)));

    if (tid < NT_) wav[tid] = x[b * NT_ + tid];
    if (tid < NREC_) {
        int rz = rec_loc[(b * NREC_ + tid) * 2 + 0];
        recown[tid] = (rz >= p * IROWS && rz < p * IROWS + IROWS) ? 1 : 0;
    }

    // cfx/cf2x for ext rows -1..4 (index 0..5): cf = vp^2*KLAP masked;
    // cf2 = 2 - 4*cf. hn = cf*((N+S)+(E+W)) + (cf2*C - P)
    v4f cfx[6], cf2x[6];
#pragma unroll
    for (int i = 0; i < 6; ++i) {
        int gr = grt + i - 1;              // ext row -1..4
        int crow = gr < 0 ? 0 : (gr > 255 ? 255 : gr);
        bool rowok = (gr >= 1) && (gr <= 254);
        v4f vv = *(const v4f*)&vp[crow * NX_ + c0];
        float cc[4];
#pragma unroll
        for (int k = 0; k < 4; ++k) {
            int col = c0 + k;
            float vk = (k == 0) ? vv.x : (k == 1) ? vv.y : (k == 2) ? vv.z : vv.w;
            cc[k] = (rowok && col >= 1 && col <= 254) ? vk * vk * KLAP : 0.f;
        }
        cfx[i].x = cc[0]; cfx[i].y = cc[1]; cfx[i].z = cc[2]; cfx[i].w = cc[3];
        cf2x[i].x = 2.f - 4.f * cc[0]; cf2x[i].y = 2.f - 4.f * cc[1];
        cf2x[i].z = 2.f - 4.f * cc[2]; cf2x[i].w = 2.f - 4.f * cc[3];
    }

    // source: si in 0..3 for finals; extended si in -1..4 for temps
    const int sz = src_loc[b * 2 + 0], sx = src_loc[b * 2 + 1];
    const int si = sz - grt;
    const int sj = sx - c0;
    const bool has_src  = ((unsigned)si < 4u) && ((unsigned)sj < 4u);
    const bool has_srcx = ((unsigned)(si + 1) < 6u) && ((unsigned)sj < 4u);
    const bool wave_has_src  = __any(has_src);
    const bool wave_has_srcx = __any(has_srcx);

    // receiver slots: interior owner only. pk=(r<<4)|(i<<2)|j
    int rs[RCAP]; int rcnt = 0;
#pragma unroll 1
    for (int r = 0; r < NREC_; ++r) {
        int rz = rec_loc[(b * NREC_ + r) * 2 + 0];
        int rx = rec_loc[(b * NREC_ + r) * 2 + 1];
        int i = rz - grt, j = rx - c0;
        if (rz >= p * IROWS && rz < p * IROWS + IROWS &&
            (unsigned)i < 4u && (unsigned)j < 4u) {
            if (rcnt < RCAP) rs[rcnt] = (r << 4) | (i << 2) | j;
            ++rcnt;
        }
    }
    if (rcnt > RCAP) rcnt = RCAP;
    const bool wave_has_rec = __any(rcnt > 0);
    float* outb = out + (size_t)b * NT_ * NREC_;

    v4f A[4], Bv[4];
    {
        v4f z = {0.f, 0.f, 0.f, 0.f};
#pragma unroll
        for (int i = 0; i < 4; ++i) { A[i] = z; Bv[i] = z; }
    }

    auto gptr = [&](int e, int bk, int lvl, int rr) -> float* {
        return gbuf + ((((size_t)(e & 1) * NBLK + bk) * 2 + lvl) * 8 + rr) * 256;
    };

// stencil: DST = cf*( (N+S)+(W+E) ) + (cf2*C - P), exact R15 association.
#define STEN(DST, NV, CV, SV, PV, CI) do {                                    \
    float wv = dpp_shr1((CV).w);                                              \
    float ev = dpp_shl1((CV).x);                                              \
    v4f hn;                                                                   \
    { float sm = ((NV).x + (SV).x) + (wv     + (CV).y);                       \
      hn.x = fmaf(cfx[CI].x, sm, fmaf(cf2x[CI].x, (CV).x, -(PV).x)); }        \
    { float sm = ((NV).y + (SV).y) + ((CV).x + (CV).z);                       \
      hn.y = fmaf(cfx[CI].y, sm, fmaf(cf2x[CI].y, (CV).y, -(PV).y)); }        \
    { float sm = ((NV).z + (SV).z) + ((CV).y + (CV).w);                       \
      hn.z = fmaf(cfx[CI].z, sm, fmaf(cf2x[CI].z, (CV).z, -(PV).z)); }        \
    { float sm = ((NV).w + (SV).w) + ((CV).z + ev);                           \
      hn.w = fmaf(cfx[CI].w, sm, fmaf(cf2x[CI].w, (CV).w, -(PV).w)); }        \
    DST = hn;                                                                 \
} while (0)

#define INJ(V, SV) do {                                                       \
    if      (sj == 0) (V).x += (SV);                                          \
    else if (sj == 1) (V).y += (SV);                                          \
    else if (sj == 2) (V).z += (SV);                                          \
    else              (V).w += (SV);                                          \
} while (0)

    // fused cycle: A=level t, Bv=level t-1 -> computes t+1 (temps, into Bv)
    // and t+2 (finals, into A). One barrier. par = (t>>1)&1.
    auto fstep = [&](int t, int par) {
        const int k1 = (t & (G - 1)) + 1;      // first step of pair: 1,3,..,15
        if (k1 - 2 <= cut) {                   // publish iff active prev cycle
            *(v4f*)&pub[par][band][0][c0] = A[0];
            *(v4f*)&pub[par][band][1][c0] = A[1];
            *(v4f*)&pub[par][band][2][c0] = Bv[0];
            *(v4f*)&pub[par][band][3][c0] = A[2];
            *(v4f*)&pub[par][band][4][c0] = A[3];
            *(v4f*)&pub[par][band][5][c0] = Bv[3];
        }
        __syncthreads();
        if (k1 > cut) return;                  // band dead for this round
        v4f nC2, nC3, nP3, sC0, sC1, sP0;
        if (band > 0) {
            nC2 = *(const v4f*)&pub[par][band - 1][3][c0];
            nC3 = *(const v4f*)&pub[par][band - 1][4][c0];
            nP3 = *(const v4f*)&pub[par][band - 1][5][c0];
        } else { v4f z = {0,0,0,0}; nC2 = z; nC3 = z; nP3 = z; }
        if (band < NB - 1) {
            sC0 = *(const v4f*)&pub[par][band + 1][0][c0];
            sC1 = *(const v4f*)&pub[par][band + 1][1][c0];
            sP0 = *(const v4f*)&pub[par][band + 1][2][c0];
        } else { v4f z = {0,0,0,0}; sC0 = z; sC1 = z; sP0 = z; }
        // temps = level t+1, rows -1..4. Local-only rows first (hide ds_read).
        v4f tm1, t0, t1, t2, t3, t4;
        STEN(t1, A[0], A[1], A[2], Bv[1], 2);
        STEN(t2, A[1], A[2], A[3], Bv[2], 3);
        STEN(t0, nC3, A[0], A[1], Bv[0], 1);
        STEN(t3, A[2], A[3], sC0, Bv[3], 4);
        STEN(tm1, nC2, nC3, A[0], nP3, 0);
        STEN(t4, A[3], sC0, sC1, sP0, 5);
        if (wave_has_srcx) {                   // inject wav[t] at level t+1
            const float sv = DT2 * wav[t];
            if (has_srcx) {
                if      (si == -1) INJ(tm1, sv);
                else if (si == 0)  INJ(t0, sv);
                else if (si == 1)  INJ(t1, sv);
                else if (si == 2)  INJ(t2, sv);
                else if (si == 3)  INJ(t3, sv);
                else               INJ(t4, sv);
            }
        }
        // prev level := t+1
        Bv[0] = t0; Bv[1] = t1; Bv[2] = t2; Bv[3] = t3;
        // finals = level t+2 (overwrite A; PV = old A row, read before write)
        STEN(A[0], tm1, t0, t1, A[0], 1);
        STEN(A[1], t0, t1, t2, A[1], 2);
        STEN(A[2], t1, t2, t3, A[2], 3);
        STEN(A[3], t2, t3, t4, A[3], 4);
        if (wave_has_src) {                    // inject wav[t+1] at level t+2
            const float sv = DT2 * wav[t + 1];
            if (has_src) {
                if      (si == 0) INJ(A[0], sv);
                else if (si == 1) INJ(A[1], sv);
                else if (si == 2) INJ(A[2], sv);
                else              INJ(A[3], sv);
            }
        }
        if (wave_has_rec) {                    // odd step from Bv, even from A
#pragma unroll
            for (int kk = 0; kk < RCAP; ++kk) {
                if (rcnt > kk) {
                    int pk = rs[kk];
                    int i = (pk >> 2) & 3, j = pk & 3, r = pk >> 4;
                    v4f o01 = (i & 1) ? Bv[1] : Bv[0];
                    v4f o23 = (i & 1) ? Bv[3] : Bv[2];
                    v4f ro  = (i & 2) ? o23 : o01;
                    float oc01 = (j & 1) ? ro.y : ro.x;
                    float oc23 = (j & 1) ? ro.w : ro.z;
                    recbuf[t & (G - 1)][r] = (j & 2) ? oc23 : oc01;
                    v4f e01 = (i & 1) ? A[1] : A[0];
                    v4f e23 = (i & 1) ? A[3] : A[2];
                    v4f re  = (i & 2) ? e23 : e01;
                    float ec01 = (j & 1) ? re.y : re.x;
                    float ec23 = (j & 1) ? re.w : re.z;
                    recbuf[(t + 1) & (G - 1)][r] = (j & 2) ? ec23 : ec01;
                }
            }
        }
    };

    // two-hop fence-free exchange (R15), now storing BOTH levels here.
    auto exchange = [&](int e) {
        if (band == 4 || band == 5) {      // publish interior, both levels
            int rr0 = (band - 4) << 2;
#pragma unroll
            for (int i = 0; i < 4; ++i) {
                store_v4_sys(&gptr(e, blk, 0, rr0 + i)[c0], A[i]);
                store_v4_sys(&gptr(e, blk, 1, rr0 + i)[c0], Bv[i]);
            }
        }
        __syncthreads();                   // drains each wave's vmcnt first
        if (tid == 0)
            __hip_atomic_store(&flags[blk], e + 1, __ATOMIC_RELAXED,
                               __HIP_MEMORY_SCOPE_SYSTEM);
        if (band < 2 && p >= 2) {          // ext rows 0..7  <- blk-2 interior
            if (lane == 0)
                while (__hip_atomic_load(&flags[blk - 2], __ATOMIC_RELAXED,
                                         __HIP_MEMORY_SCOPE_SYSTEM) < e + 1)
                    __builtin_amdgcn_s_sleep(1);
            int rr0 = band << 2;
#pragma unroll
            for (int i = 0; i < 4; ++i) {
                A[i]  = load_v4_sys(&gptr(e, blk - 2, 0, rr0 + i)[c0]);
                Bv[i] = load_v4_sys(&gptr(e, blk - 2, 1, rr0 + i)[c0]);
            }
        }
        if (band >= 2 && band < 4 && p >= 1) {  // ext rows 8..15 <- blk-1
            if (lane == 0)
                while (__hip_atomic_load(&flags[blk - 1], __ATOMIC_RELAXED,
                                         __HIP_MEMORY_SCOPE_SYSTEM) < e + 1)
                    __builtin_amdgcn_s_sleep(1);
            int rr0 = (band - 2) << 2;
#pragma unroll
            for (int i = 0; i < 4; ++i) {
                A[i]  = load_v4_sys(&gptr(e, blk - 1, 0, rr0 + i)[c0]);
                Bv[i] = load_v4_sys(&gptr(e, blk - 1, 1, rr0 + i)[c0]);
            }
        }
        if (band >= 6 && band < 8 && p < PIECES - 1) {  // ext 24..31 <- blk+1
            if (lane == 0)
                while (__hip_atomic_load(&flags[blk + 1], __ATOMIC_RELAXED,
                                         __HIP_MEMORY_SCOPE_SYSTEM) < e + 1)
                    __builtin_amdgcn_s_sleep(1);
            int rr0 = (band - 6) << 2;
#pragma unroll
            for (int i = 0; i < 4; ++i) {
                A[i]  = load_v4_sys(&gptr(e, blk + 1, 0, rr0 + i)[c0]);
                Bv[i] = load_v4_sys(&gptr(e, blk + 1, 1, rr0 + i)[c0]);
            }
        }
        if (band >= 8 && p < PIECES - 2) {  // ext rows 32..39 <- blk+2
            if (lane == 0)
                while (__hip_atomic_load(&flags[blk + 2], __ATOMIC_RELAXED,
                                         __HIP_MEMORY_SCOPE_SYSTEM) < e + 1)
                    __builtin_amdgcn_s_sleep(1);
            int rr0 = (band - 8) << 2;
#pragma unroll
            for (int i = 0; i < 4; ++i) {
                A[i]  = load_v4_sys(&gptr(e, blk + 2, 0, rr0 + i)[c0]);
                Bv[i] = load_v4_sys(&gptr(e, blk + 2, 1, rr0 + i)[c0]);
            }
        }
        asm volatile("s_waitcnt vmcnt(0)" ::: "memory");  // rule #18
        __builtin_amdgcn_sched_barrier(0);
        __syncthreads();
    };

    int t = 0;
#pragma unroll 1
    for (int e = 0; e < ROUNDS; ++e) {
#pragma unroll 1
        for (int c = 0; c < G / 2; ++c) {
            fstep(t, (t >> 1) & 1);
            t += 2;
        }
        __syncthreads();           // recbuf writes from scattered owners
#pragma unroll 1
        for (int idx = tid; idx < G * NREC_; idx += NTHR) {
            int s = idx >> 6, r = idx & 63;
            if (recown[r]) outb[(e * G + s) * NREC_ + r] = recbuf[s][r];
        }
        if (e < ROUNDS - 1) exchange(e);
    }
#undef STEN
#undef INJ
}

extern "C" void kernel_launch(void* const* d_in, const int* in_sizes, int n_in,
                              void* d_out, int out_size, void* d_ws, size_t ws_size,
                              hipStream_t stream) {
    const float* x   = (const float*)d_in[0];
    const float* vp  = (const float*)d_in[1];
    const int*   src = (const int*)d_in[2];
    const int*   rec = (const int*)d_in[3];
    float*       o   = (float*)d_out;
    int*   flags = (int*)d_ws;
    float* gbuf  = (float*)((char*)d_ws + FLAGS_BYTES);
    (void)hipMemsetAsync(d_ws, 0, FLAGS_BYTES, stream);   // flags must start at 0
    hipLaunchKernelGGL(wave_reg_kernel, dim3(NBLK), dim3(NTHR), 0, stream,
                       x, vp, src, rec, o, flags, gbuf);
}